// Round 2
// 418.038 us; speedup vs baseline: 1.0507x; 1.0507x over previous
//
#include <hip/hip_runtime.h>
#include <math.h>

// ============================================================================
// ViT block on MI355X — Round 5 (resubmit; prior bench failed on infra):
//   * GEMM/patch kernels: BK=64 (halves vmcnt(0)+barrier drains per K; the
//     K=256/1024 shapes only had 8/32 iterations at BK=32, so the per-iter
//     drain dominated). kh sub-loop keeps fragment VGPRs at 8x short8.
//   * LDS XOR swizzle (both-sides: pre-swizzled global src + swizzled read)
//     keeps ds_read_b128 at the wave64 floor (linear 128B rows would be
//     16-way conflicted).
//   * 5 weight-cvt launches merged into 1.
//   * Everything else (attention, LN+PE, layouts, workspace) unchanged.
// ============================================================================

#define M_TOK 32768

typedef __attribute__((ext_vector_type(8))) short  short8;   // 8 bf16 (4 VGPRs)
typedef __attribute__((ext_vector_type(4))) float  f32x4;
typedef __attribute__((ext_vector_type(8))) unsigned short us8v;
typedef __attribute__((ext_vector_type(4))) unsigned short us4v;

__device__ __forceinline__ unsigned short f2b(float f) {
    union { float f; unsigned u; } c; c.f = f;
    unsigned r = c.u + 0x7fffu + ((c.u >> 16) & 1u);   // RNE
    return (unsigned short)(r >> 16);
}
__device__ __forceinline__ float gelu_fast(float x) {
    // 0.5x(1+tanh(c0(x+0.044715x^3))) == x * sigmoid(2*c0*(x+0.044715x^3))
    const float c0 = 0.7978845608028654f;            // sqrt(2/pi)
    const float c1 = 0.044715f * 0.7978845608028654f;
    float z = x * (c0 + c1 * x * x);
    float e = __expf(-2.0f * z);
    return x * __builtin_amdgcn_rcpf(1.0f + e);
}
// async global->LDS, 16B per lane; lds dest must be wave-uniform base (+lane*16 by HW)
__device__ __forceinline__ void load_lds16(const unsigned short* g, void* lds) {
    __builtin_amdgcn_global_load_lds(
        (const __attribute__((address_space(1))) unsigned int*)g,
        (__attribute__((address_space(3))) unsigned int*)lds, 16, 0, 0);
}

// ---------------------------------------------------------------------------
// fp32 -> bf16 convert (n % 4 == 0) — used for the big image tensor only
// ---------------------------------------------------------------------------
__global__ __launch_bounds__(256) void cvt_f2b_kernel(
    const float* __restrict__ in, unsigned short* __restrict__ out, int n)
{
    int i = (blockIdx.x * 256 + threadIdx.x) * 4;
    if (i >= n) return;
    float4 v = *(const float4*)(in + i);
    us4v o;
    o[0] = f2b(v.x); o[1] = f2b(v.y); o[2] = f2b(v.z); o[3] = f2b(v.w);
    *(us4v*)(out + i) = o;
}

// ---------------------------------------------------------------------------
// All 5 weight tensors converted in ONE launch (ranges in 1024-elem blocks):
//   conv_w 196608 -> 192 | qkv_w 196608 -> 192 | proj_w 65536 -> 64
//   ff_w1 262144 -> 256  | ff_w2 262144 -> 256   (total 960 blocks)
// ---------------------------------------------------------------------------
__global__ __launch_bounds__(256) void cvt_weights_kernel(
    const float* __restrict__ s0, const float* __restrict__ s1,
    const float* __restrict__ s2, const float* __restrict__ s3,
    const float* __restrict__ s4,
    unsigned short* __restrict__ d0, unsigned short* __restrict__ d1,
    unsigned short* __restrict__ d2, unsigned short* __restrict__ d3,
    unsigned short* __restrict__ d4)
{
    const int bid = blockIdx.x;
    const float* src; unsigned short* dst; int off;
    if      (bid < 192) { src = s0; dst = d0; off = bid; }
    else if (bid < 384) { src = s1; dst = d1; off = bid - 192; }
    else if (bid < 448) { src = s2; dst = d2; off = bid - 384; }
    else if (bid < 704) { src = s3; dst = d3; off = bid - 448; }
    else                { src = s4; dst = d4; off = bid - 704; }
    const int i = off * 1024 + threadIdx.x * 4;
    float4 v = *(const float4*)(src + i);
    us4v o;
    o[0] = f2b(v.x); o[1] = f2b(v.y); o[2] = f2b(v.z); o[3] = f2b(v.w);
    *(us4v*)(dst + i) = o;
}

// ---------------------------------------------------------------------------
// Sinusoidal PE table: pe[pos][d], pos<1024, d<256.
// ---------------------------------------------------------------------------
__global__ __launch_bounds__(256) void pe_init_kernel(float* __restrict__ pe)
{
    const int pos = blockIdx.x;
    const int d   = threadIdx.x;
    const int ieven = d & ~1;
    float div = expf(-9.210340371976184f * (float)ieven * (1.0f / 256.0f));
    float ang = (float)pos * div;
    pe[pos * 256 + d] = (d & 1) ? cosf(ang) : sinf(ang);
}

// ---------------------------------------------------------------------------
// MFMA GEMM: C = A (MxK) . W^T (NxK) + bias (+gelu/res)
// 128x128 tile, BK=64, 256 thr = 4 waves 2x2.
// LDS [128][64] bf16 per operand with XOR swizzle:
//   stored-at(row, col) = row*64 + (col ^ ((row&7)*8))   [shorts]
// Staging round s (4 rounds/operand): wave wv lane l writes linear LDS
//   s*4096 + wv*1024 + l*16 bytes -> row = s*32 + wv*8 + (l>>3),
//   so the GLOBAL source k-chunk must be pre-swizzled:
//   skk = ((l&7) ^ ((l>>3)&7)) * 8.
// ---------------------------------------------------------------------------
template<bool GELU, bool RES, bool WF32, bool WB16>
__global__ __launch_bounds__(256) void mfma_gemm_kernel(
    const unsigned short* __restrict__ A, const unsigned short* __restrict__ W,
    const float* __restrict__ bias, const float* __restrict__ res,
    float* __restrict__ outF, unsigned short* __restrict__ outB,
    int M, int N, int K)
{
    __shared__ unsigned short As[128 * 64];
    __shared__ unsigned short Ws[128 * 64];

    const int t    = threadIdx.x;
    const int m0   = blockIdx.x * 128;
    const int n0   = blockIdx.y * 128;
    const int wv   = t >> 6, lane = t & 63;
    const int wr   = (wv >> 1) * 64, wc = (wv & 1) * 64;
    const int l15  = lane & 15, quad = lane >> 4;

    f32x4 acc[4][4];
#pragma unroll
    for (int i = 0; i < 4; i++)
#pragma unroll
        for (int j = 0; j < 4; j++)
#pragma unroll
            for (int r = 0; r < 4; r++) acc[i][j][r] = 0.0f;

    // staging map (round s): row = s*32 + wv*8 + (lane>>3), swizzled k-chunk
    const int srow = wv * 8 + (lane >> 3);
    const int skk  = (((lane & 7) ^ ((lane >> 3) & 7)) * 8);
    const unsigned short* gA = A + (size_t)(m0 + srow) * K + skk;
    const unsigned short* gW = W + (size_t)(n0 + srow) * K + skk;
    char* lA = (char*)As + wv * 1024;
    char* lW = (char*)Ws + wv * 1024;

    const int cswz = (l15 & 7) * 8;   // read-side XOR (shorts)

    for (int k0 = 0; k0 < K; k0 += 64) {
        __syncthreads();                 // prior iter's ds_reads done
#pragma unroll
        for (int s = 0; s < 4; s++) {
            load_lds16(gA + (size_t)(s * 32) * K + k0, lA + s * 4096);
            load_lds16(gW + (size_t)(s * 32) * K + k0, lW + s * 4096);
        }
        __syncthreads();                 // drains vmcnt -> LDS visible

#pragma unroll
        for (int kh = 0; kh < 2; kh++) {
            const int coff = (kh * 32 + quad * 8) ^ cswz;
            short8 af[4], wf[4];
#pragma unroll
            for (int i = 0; i < 4; i++)
                af[i] = *(const short8*)&As[(wr + i * 16 + l15) * 64 + coff];
#pragma unroll
            for (int j = 0; j < 4; j++)
                wf[j] = *(const short8*)&Ws[(wc + j * 16 + l15) * 64 + coff];
#pragma unroll
            for (int i = 0; i < 4; i++)
#pragma unroll
                for (int j = 0; j < 4; j++)
                    acc[i][j] = __builtin_amdgcn_mfma_f32_16x16x32_bf16(
                        af[i], wf[j], acc[i][j], 0, 0, 0);
        }
    }

#pragma unroll
    for (int i = 0; i < 4; i++) {
        const int gr = m0 + wr + i * 16 + quad * 4;
#pragma unroll
        for (int j = 0; j < 4; j++) {
            const int gc = n0 + wc + j * 16 + l15;
            const float bv = bias[gc];
#pragma unroll
            for (int r = 0; r < 4; r++) {
                float v = acc[i][j][r] + bv;
                if (GELU) v = gelu_fast(v);
                if (RES)  v += res[(size_t)(gr + r) * N + gc];
                if (WF32) outF[(size_t)(gr + r) * N + gc] = v;
                if (WB16) outB[(size_t)(gr + r) * N + gc] = f2b(v);
            }
        }
    }
}

// ---------------------------------------------------------------------------
// Patch-embed MFMA GEMM: A gathered from bf16 image xb, W = conv_w bf16.
// Same BK=64 + swizzle structure; A source address is a per-lane gather.
// ---------------------------------------------------------------------------
__global__ __launch_bounds__(256) void patch_mfma_kernel(
    const unsigned short* __restrict__ xb, const unsigned short* __restrict__ W,
    const float* __restrict__ bias, float* __restrict__ outF)
{
    __shared__ unsigned short As[128 * 64];
    __shared__ unsigned short Ws[128 * 64];

    const int t    = threadIdx.x;
    const int m0   = blockIdx.x * 128;
    const int n0   = blockIdx.y * 128;
    const int wv   = t >> 6, lane = t & 63;
    const int wr   = (wv >> 1) * 64, wc = (wv & 1) * 64;
    const int l15  = lane & 15, quad = lane >> 4;

    f32x4 acc[4][4];
#pragma unroll
    for (int i = 0; i < 4; i++)
#pragma unroll
        for (int j = 0; j < 4; j++)
#pragma unroll
            for (int r = 0; r < 4; r++) acc[i][j][r] = 0.0f;

    const int srow = wv * 8 + (lane >> 3);
    const int skk  = (((lane & 7) ^ ((lane >> 3) & 7)) * 8);  // swizzled k-chunk
    size_t xoff[4];
#pragma unroll
    for (int s = 0; s < 4; s++) {
        const int m  = m0 + s * 32 + srow;
        const int b  = m >> 10;
        const int idx = m & 1023;
        const int hh = idx >> 5, ww = idx & 31;
        xoff[s] = ((size_t)(b * 3) * 512 + (size_t)(hh * 16)) * 512 + ww * 16;
    }
    const unsigned short* gW = W + (size_t)(n0 + srow) * 768 + skk;
    char* lA = (char*)As + wv * 1024;
    char* lW = (char*)Ws + wv * 1024;

    const int cswz = (l15 & 7) * 8;

    for (int k0 = 0; k0 < 768; k0 += 64) {
        const int k  = k0 + skk;        // 8-aligned, stays within one 16-px row
        const int c  = k >> 8;
        const int ph = (k >> 4) & 15;
        const int pw = k & 15;          // 0 or 8
        const size_t koff = (size_t)c * 262144 + (size_t)ph * 512 + pw;
        __syncthreads();
#pragma unroll
        for (int s = 0; s < 4; s++) {
            load_lds16(xb + xoff[s] + koff, lA + s * 4096);
            load_lds16(gW + (size_t)(s * 32) * 768 + k0, lW + s * 4096);
        }
        __syncthreads();

#pragma unroll
        for (int kh = 0; kh < 2; kh++) {
            const int coff = (kh * 32 + quad * 8) ^ cswz;
            short8 af[4], wf[4];
#pragma unroll
            for (int i = 0; i < 4; i++)
                af[i] = *(const short8*)&As[(wr + i * 16 + l15) * 64 + coff];
#pragma unroll
            for (int j = 0; j < 4; j++)
                wf[j] = *(const short8*)&Ws[(wc + j * 16 + l15) * 64 + coff];
#pragma unroll
            for (int i = 0; i < 4; i++)
#pragma unroll
                for (int j = 0; j < 4; j++)
                    acc[i][j] = __builtin_amdgcn_mfma_f32_16x16x32_bf16(
                        af[i], wf[j], acc[i][j], 0, 0, 0);
        }
    }

#pragma unroll
    for (int i = 0; i < 4; i++) {
        const int gr = m0 + wr + i * 16 + quad * 4;
#pragma unroll
        for (int j = 0; j < 4; j++) {
            const int gc = n0 + wc + j * 16 + l15;
            const float bv = bias[gc];
#pragma unroll
            for (int r = 0; r < 4; r++)
                outF[(size_t)(gr + r) * 256 + gc] = acc[i][j][r] + bv;
        }
    }
}

// ---------------------------------------------------------------------------
// LayerNorm + PE (table lookup). One block = one token (256 features).
// ---------------------------------------------------------------------------
__global__ __launch_bounds__(256) void ln_pe_kernel(
    const float* __restrict__ in, const float* __restrict__ w,
    const float* __restrict__ b, const float* __restrict__ pe_t,
    float* __restrict__ outF, unsigned short* __restrict__ outB)
{
    const int m = blockIdx.x;
    const int d = threadIdx.x;
    float v = in[(size_t)m * 256 + d];

    float s = v, s2 = v * v;
#pragma unroll
    for (int off = 32; off > 0; off >>= 1) {
        s  += __shfl_down(s,  off, 64);
        s2 += __shfl_down(s2, off, 64);
    }
    __shared__ float ss[4], ss2[4], stats[2];
    const int lane = d & 63, wid = d >> 6;
    if (lane == 0) { ss[wid] = s; ss2[wid] = s2; }
    __syncthreads();
    if (d == 0) {
        float a  = ss[0] + ss[1] + ss[2] + ss[3];
        float a2 = ss2[0] + ss2[1] + ss2[2] + ss2[3];
        float mean = a * (1.0f / 256.0f);
        float var  = a2 * (1.0f / 256.0f) - mean * mean;
        stats[0] = mean;
        stats[1] = rsqrtf(var + 1e-5f);
    }
    __syncthreads();
    const float mean = stats[0], rstd = stats[1];

    const int pos = m & 1023;
    float pe = pe_t[pos * 256 + d];

    float o = (v - mean) * rstd * w[d] + b[d] + pe;
    outF[(size_t)m * 256 + d] = o;
    outB[(size_t)m * 256 + d] = f2b(o);
}

// ---------------------------------------------------------------------------
// MFMA windowed attention. One block = one (batch, window, head).
// ---------------------------------------------------------------------------
__global__ __launch_bounds__(256) void attn_mfma_kernel(
    const unsigned short* __restrict__ qkv, unsigned short* __restrict__ out)
{
    __shared__ unsigned short Ps[64 * 72];   // P, stride 72 (b128-aligned, padded)
    __shared__ unsigned short Vt[32 * 72];   // V^T [headdim][key]

    const int blk = blockIdx.x;        // 0..4095
    const int h = blk & 7;
    const int w = (blk >> 3) & 15;
    const int b = blk >> 7;
    const int m_base = b * 1024 + w * 64;

    const int t = threadIdx.x;
    const int wv = t >> 6, lane = t & 63;
    const int l15 = lane & 15, quad = lane >> 4;

    // ---- stage V^T (cooperative, 8 elems/thread) ----
    {
        const int row = t >> 2;             // key 0..63
        const int c0  = (t & 3) * 8;        // headdim chunk
        const unsigned short* src = qkv + (size_t)(m_base + row) * 768 + 512 + h * 32 + c0;
        us8v v = *(const us8v*)src;
#pragma unroll
        for (int j = 0; j < 8; j++) Vt[(c0 + j) * 72 + row] = v[j];
    }

    // ---- QK^T: S strip (16x64) = 4 MFMAs ----
    short8 aq = *(const short8*)(qkv + (size_t)(m_base + wv * 16 + l15) * 768 + h * 32 + quad * 8);
    f32x4 c[4];
#pragma unroll
    for (int j = 0; j < 4; j++) {
        short8 bk = *(const short8*)(qkv + (size_t)(m_base + j * 16 + l15) * 768 + 256 + h * 32 + quad * 8);
        f32x4 z = {0.0f, 0.0f, 0.0f, 0.0f};
        c[j] = __builtin_amdgcn_mfma_f32_16x16x32_bf16(aq, bk, z, 0, 0, 0);
    }

    // ---- softmax over keys (row = quad*4+reg, col = j*16+l15) ----
    const float scale = 0.17677669529663687f; // 1/sqrt(32)
    float sm[4];
#pragma unroll
    for (int r = 0; r < 4; r++) {
        float m0 = -1e30f;
#pragma unroll
        for (int j = 0; j < 4; j++) { c[j][r] *= scale; m0 = fmaxf(m0, c[j][r]); }
#pragma unroll
        for (int d = 1; d < 16; d <<= 1) m0 = fmaxf(m0, __shfl_xor(m0, d, 64));
        float s0 = 0.0f;
#pragma unroll
        for (int j = 0; j < 4; j++) { float e = __expf(c[j][r] - m0); c[j][r] = e; s0 += e; }
#pragma unroll
        for (int d = 1; d < 16; d <<= 1) s0 += __shfl_xor(s0, d, 64);
        sm[r] = __builtin_amdgcn_rcpf(s0);
    }

    // ---- write P (bf16) to LDS ----
#pragma unroll
    for (int r = 0; r < 4; r++) {
        const int prow = wv * 16 + quad * 4 + r;
#pragma unroll
        for (int j = 0; j < 4; j++)
            Ps[prow * 72 + j * 16 + l15] = f2b(c[j][r] * sm[r]);
    }
    __syncthreads();

    // ---- PV: O strip (16x32) = 4 MFMAs ----
    short8 ap0 = *(const short8*)&Ps[(wv * 16 + l15) * 72 + quad * 8];
    short8 ap1 = *(const short8*)&Ps[(wv * 16 + l15) * 72 + 32 + quad * 8];
    f32x4 o[2];
#pragma unroll
    for (int nt = 0; nt < 2; nt++) {
        short8 bv0 = *(const short8*)&Vt[(nt * 16 + l15) * 72 + quad * 8];
        short8 bv1 = *(const short8*)&Vt[(nt * 16 + l15) * 72 + 32 + quad * 8];
        f32x4 z = {0.0f, 0.0f, 0.0f, 0.0f};
        o[nt] = __builtin_amdgcn_mfma_f32_16x16x32_bf16(ap0, bv0, z, 0, 0, 0);
        o[nt] = __builtin_amdgcn_mfma_f32_16x16x32_bf16(ap1, bv1, o[nt], 0, 0, 0);
    }

    // ---- write O (bf16) ----
#pragma unroll
    for (int nt = 0; nt < 2; nt++) {
#pragma unroll
        for (int r = 0; r < 4; r++) {
            const int row = m_base + wv * 16 + quad * 4 + r;
            out[(size_t)row * 256 + h * 32 + nt * 16 + l15] = f2b(o[nt][r]);
        }
    }
}

// ---------------------------------------------------------------------------
// Workspace layout (bytes), total ~186.5 MB (unchanged from round 4).
// ---------------------------------------------------------------------------
extern "C" void kernel_launch(void* const* d_in, const int* in_sizes, int n_in,
                              void* d_out, int out_size, void* d_ws, size_t ws_size,
                              hipStream_t stream)
{
    const float* x      = (const float*)d_in[0];
    const float* conv_w = (const float*)d_in[1];
    const float* conv_b = (const float*)d_in[2];
    const float* ln_w   = (const float*)d_in[3];
    const float* ln_b   = (const float*)d_in[4];
    const float* qkv_w  = (const float*)d_in[5];
    const float* qkv_b  = (const float*)d_in[6];
    const float* proj_w = (const float*)d_in[7];
    const float* proj_b = (const float*)d_in[8];
    const float* ff_w1  = (const float*)d_in[9];
    const float* ff_b1  = (const float*)d_in[10];
    const float* ff_w2  = (const float*)d_in[11];
    const float* ff_b2  = (const float*)d_in[12];
    float* out = (float*)d_out;

    char* ws = (char*)d_ws;
    unsigned short* xb    = (unsigned short*)(ws);                 // SLOT_A
    unsigned short* hidb  = (unsigned short*)(ws);                 // SLOT_A reuse
    float*          h0    = (float*)(ws + 67108864);               // SLOT_B
    unsigned short* qkvb  = (unsigned short*)(ws + 67108864);      // SLOT_B reuse
    float*          pe_t  = (float*)(ws + 100663296);              // SLOT_B tail
    float*          h1f   = (float*)(ws + 117440512);
    unsigned short* h1b   = (unsigned short*)(ws + 150994944);     // SLOT_C
    unsigned short* aob   = (unsigned short*)(ws + 150994944);     // SLOT_C reuse
    unsigned short* f1b   = (unsigned short*)(ws + 167772160);     // SLOT_D
    unsigned short* h2b   = (unsigned short*)(ws + 167772160);     // SLOT_D reuse
    unsigned short* wbase = (unsigned short*)(ws + 184549376);
    unsigned short* conv_wb = wbase;                 // 196608
    unsigned short* qkv_wb  = wbase + 196608;        // 196608
    unsigned short* proj_wb = wbase + 393216;        // 65536
    unsigned short* ff_w1b  = wbase + 458752;        // 262144
    unsigned short* ff_w2b  = wbase + 720896;        // 262144

    const int M = M_TOK;
    dim3 blk(256);

    // K0: conversions + PE table
    cvt_f2b_kernel<<<dim3(25165824 / 1024), blk, 0, stream>>>(x, xb, 25165824);
    cvt_weights_kernel<<<dim3(960), blk, 0, stream>>>(
        conv_w, qkv_w, proj_w, ff_w1, ff_w2,
        conv_wb, qkv_wb, proj_wb, ff_w1b, ff_w2b);
    pe_init_kernel<<<dim3(1024), blk, 0, stream>>>(pe_t);

    // K1: patch embed -> h0 (fp32)
    patch_mfma_kernel<<<dim3(M / 128, 2), blk, 0, stream>>>(xb, conv_wb, conv_b, h0);
    // K2: LN + PE -> h1f (fp32 residual) + h1b (bf16)
    ln_pe_kernel<<<dim3(M), blk, 0, stream>>>(h0, ln_w, ln_b, pe_t, h1f, h1b);
    // K3: FFN1a: gelu(h1 @ w1^T + b1) -> hidb (bf16)
    mfma_gemm_kernel<true, false, false, true><<<dim3(M / 128, 8), blk, 0, stream>>>(
        h1b, ff_w1b, ff_b1, nullptr, nullptr, hidb, M, 1024, 256);
    // K4: FFN1b: hidb @ w2^T + b2 -> f1b (bf16)
    mfma_gemm_kernel<false, false, false, true><<<dim3(M / 128, 2), blk, 0, stream>>>(
        hidb, ff_w2b, ff_b2, nullptr, nullptr, f1b, M, 256, 1024);
    // K5: qkv: f1b @ qkv_w^T + qkv_b -> qkvb (bf16)
    mfma_gemm_kernel<false, false, false, true><<<dim3(M / 128, 6), blk, 0, stream>>>(
        f1b, qkv_wb, qkv_b, nullptr, nullptr, qkvb, M, 768, 256);
    // K6: windowed attention (MFMA): qkvb -> aob (bf16)
    attn_mfma_kernel<<<dim3(4096), blk, 0, stream>>>(qkvb, aob);
    // K7: proj + residual(h1f): aob @ proj_w^T + proj_b + h1f -> out + h2b
    mfma_gemm_kernel<false, true, true, true><<<dim3(M / 128, 2), blk, 0, stream>>>(
        aob, proj_wb, proj_b, h1f, out, h2b, M, 256, 256);
    // K8: FFN2a: gelu(h2b @ w1^T + b1) -> hidb (bf16)
    mfma_gemm_kernel<true, false, false, true><<<dim3(M / 128, 8), blk, 0, stream>>>(
        h2b, ff_w1b, ff_b1, nullptr, nullptr, hidb, M, 1024, 256);
    // K9: FFN2b + final residual: hidb @ w2^T + b2 + out -> out
    mfma_gemm_kernel<false, true, true, false><<<dim3(M / 128, 2), blk, 0, stream>>>(
        hidb, ff_w2b, ff_b2, out, out, nullptr, M, 256, 1024);
}

// Round 3
// 405.983 us; speedup vs baseline: 1.0819x; 1.0297x over previous
//
#include <hip/hip_runtime.h>
#include <math.h>

// ============================================================================
// ViT block on MI355X — Round 6:
//   * GEMM/patch K-loops rebuilt as issue-early double-buffered 2-phase
//     (T3 minimum): stage tile t+1 BEFORE computing tile t; raw s_barrier +
//     counted s_waitcnt vmcnt(8) instead of __syncthreads' vmcnt(0) drain.
//     Each stage gets a full compute phase to cover HBM latency.
//   * LDS 64 KB/block (2 buffers x (As+Ws)); t-loop unrolled x2 (nt always
//     even: 4/12/16) so buffer addressing is static.
//   * Epilogues, attention, LN+PE, cvt, workspace unchanged from round 5.
// ============================================================================

#define M_TOK 32768

typedef __attribute__((ext_vector_type(8))) short  short8;   // 8 bf16 (4 VGPRs)
typedef __attribute__((ext_vector_type(4))) float  f32x4;
typedef __attribute__((ext_vector_type(8))) unsigned short us8v;
typedef __attribute__((ext_vector_type(4))) unsigned short us4v;

__device__ __forceinline__ unsigned short f2b(float f) {
    union { float f; unsigned u; } c; c.f = f;
    unsigned r = c.u + 0x7fffu + ((c.u >> 16) & 1u);   // RNE
    return (unsigned short)(r >> 16);
}
__device__ __forceinline__ float gelu_fast(float x) {
    // 0.5x(1+tanh(c0(x+0.044715x^3))) == x * sigmoid(2*c0*(x+0.044715x^3))
    const float c0 = 0.7978845608028654f;            // sqrt(2/pi)
    const float c1 = 0.044715f * 0.7978845608028654f;
    float z = x * (c0 + c1 * x * x);
    float e = __expf(-2.0f * z);
    return x * __builtin_amdgcn_rcpf(1.0f + e);
}
// async global->LDS, 16B per lane; lds dest must be wave-uniform base (+lane*16 by HW)
__device__ __forceinline__ void load_lds16(const unsigned short* g, void* lds) {
    __builtin_amdgcn_global_load_lds(
        (const __attribute__((address_space(1))) unsigned int*)g,
        (__attribute__((address_space(3))) unsigned int*)lds, 16, 0, 0);
}

// ---------------------------------------------------------------------------
// fp32 -> bf16 convert (n % 4 == 0) — used for the big image tensor only
// ---------------------------------------------------------------------------
__global__ __launch_bounds__(256) void cvt_f2b_kernel(
    const float* __restrict__ in, unsigned short* __restrict__ out, int n)
{
    int i = (blockIdx.x * 256 + threadIdx.x) * 4;
    if (i >= n) return;
    float4 v = *(const float4*)(in + i);
    us4v o;
    o[0] = f2b(v.x); o[1] = f2b(v.y); o[2] = f2b(v.z); o[3] = f2b(v.w);
    *(us4v*)(out + i) = o;
}

// ---------------------------------------------------------------------------
// All 5 weight tensors converted in ONE launch (ranges in 1024-elem blocks):
//   conv_w 196608 -> 192 | qkv_w 196608 -> 192 | proj_w 65536 -> 64
//   ff_w1 262144 -> 256  | ff_w2 262144 -> 256   (total 960 blocks)
// ---------------------------------------------------------------------------
__global__ __launch_bounds__(256) void cvt_weights_kernel(
    const float* __restrict__ s0, const float* __restrict__ s1,
    const float* __restrict__ s2, const float* __restrict__ s3,
    const float* __restrict__ s4,
    unsigned short* __restrict__ d0, unsigned short* __restrict__ d1,
    unsigned short* __restrict__ d2, unsigned short* __restrict__ d3,
    unsigned short* __restrict__ d4)
{
    const int bid = blockIdx.x;
    const float* src; unsigned short* dst; int off;
    if      (bid < 192) { src = s0; dst = d0; off = bid; }
    else if (bid < 384) { src = s1; dst = d1; off = bid - 192; }
    else if (bid < 448) { src = s2; dst = d2; off = bid - 384; }
    else if (bid < 704) { src = s3; dst = d3; off = bid - 448; }
    else                { src = s4; dst = d4; off = bid - 704; }
    const int i = off * 1024 + threadIdx.x * 4;
    float4 v = *(const float4*)(src + i);
    us4v o;
    o[0] = f2b(v.x); o[1] = f2b(v.y); o[2] = f2b(v.z); o[3] = f2b(v.w);
    *(us4v*)(dst + i) = o;
}

// ---------------------------------------------------------------------------
// Sinusoidal PE table: pe[pos][d], pos<1024, d<256.
// ---------------------------------------------------------------------------
__global__ __launch_bounds__(256) void pe_init_kernel(float* __restrict__ pe)
{
    const int pos = blockIdx.x;
    const int d   = threadIdx.x;
    const int ieven = d & ~1;
    float div = expf(-9.210340371976184f * (float)ieven * (1.0f / 256.0f));
    float ang = (float)pos * div;
    pe[pos * 256 + d] = (d & 1) ? cosf(ang) : sinf(ang);
}

// ---------------------------------------------------------------------------
// MFMA GEMM: C = A (MxK) . W^T (NxK) + bias (+gelu/res)
// 128x128 tile, BK=64, 256 thr = 4 waves 2x2, double-buffered LDS (64 KB).
// Per-buffer LDS [128][64] bf16 with XOR swizzle:
//   stored-at(row, col) = row*64 + (col ^ ((row&7)*8))   [shorts]
// Staging round s: wave wv lane l writes linear LDS bytes
//   s*4096 + wv*1024 + l*16 -> row = s*32 + wv*8 + (l>>3); global source
//   k-chunk pre-swizzled: skk = ((l&7) ^ ((l>>3)&7)) * 8.
// Pipeline (nt even): stage(t+1) -> vmcnt(8) [tile t done] -> barrier ->
//   compute(t) -> barrier -> swap. Counted vmcnt keeps next tile's loads
//   in flight across the barrier (no __syncthreads vmcnt(0) drain).
// ---------------------------------------------------------------------------
template<bool GELU, bool RES, bool WF32, bool WB16>
__global__ __launch_bounds__(256) void mfma_gemm_kernel(
    const unsigned short* __restrict__ A, const unsigned short* __restrict__ W,
    const float* __restrict__ bias, const float* __restrict__ res,
    float* __restrict__ outF, unsigned short* __restrict__ outB,
    int M, int N, int K)
{
    __shared__ unsigned short As[2 * 128 * 64];
    __shared__ unsigned short Ws[2 * 128 * 64];

    const int t    = threadIdx.x;
    const int m0   = blockIdx.x * 128;
    const int n0   = blockIdx.y * 128;
    const int wv   = t >> 6, lane = t & 63;
    const int wr   = (wv >> 1) * 64, wc = (wv & 1) * 64;
    const int l15  = lane & 15, quad = lane >> 4;

    f32x4 acc[4][4];
#pragma unroll
    for (int i = 0; i < 4; i++)
#pragma unroll
        for (int j = 0; j < 4; j++)
#pragma unroll
            for (int r = 0; r < 4; r++) acc[i][j][r] = 0.0f;

    // staging map (round s): row = s*32 + wv*8 + (lane>>3), swizzled k-chunk
    const int srow = wv * 8 + (lane >> 3);
    const int skk  = (((lane & 7) ^ ((lane >> 3) & 7)) * 8);
    const unsigned short* gA = A + (size_t)(m0 + srow) * K + skk;
    const unsigned short* gW = W + (size_t)(n0 + srow) * K + skk;
    char* lA = (char*)As + wv * 1024;      // + buf*16384 + s*4096
    char* lW = (char*)Ws + wv * 1024;

    const int cswz = (l15 & 7) * 8;        // read-side XOR (shorts)
    const int nt   = K >> 6;               // 4, 12, or 16 (always even)

#define GSTAGE(tt, BUFOFF)                                                     \
    {                                                                          \
        const int kk = (tt) << 6;                                              \
        _Pragma("unroll")                                                      \
        for (int s = 0; s < 4; s++) {                                          \
            load_lds16(gA + (size_t)(s * 32) * K + kk, lA + (BUFOFF) + s * 4096); \
            load_lds16(gW + (size_t)(s * 32) * K + kk, lW + (BUFOFF) + s * 4096); \
        }                                                                      \
    }

#define GCOMPUTE(Ab, Wb)                                                       \
    {                                                                          \
        _Pragma("unroll")                                                      \
        for (int kh = 0; kh < 2; kh++) {                                       \
            const int coff = (kh * 32 + quad * 8) ^ cswz;                      \
            short8 af[4], wf[4];                                               \
            _Pragma("unroll")                                                  \
            for (int i = 0; i < 4; i++)                                        \
                af[i] = *(const short8*)&(Ab)[(wr + i * 16 + l15) * 64 + coff];\
            _Pragma("unroll")                                                  \
            for (int j = 0; j < 4; j++)                                        \
                wf[j] = *(const short8*)&(Wb)[(wc + j * 16 + l15) * 64 + coff];\
            _Pragma("unroll")                                                  \
            for (int i = 0; i < 4; i++)                                        \
                _Pragma("unroll")                                              \
                for (int j = 0; j < 4; j++)                                    \
                    acc[i][j] = __builtin_amdgcn_mfma_f32_16x16x32_bf16(       \
                        af[i], wf[j], acc[i][j], 0, 0, 0);                     \
        }                                                                      \
    }

    GSTAGE(0, 0);                               // prologue: tile 0 -> buf0
    for (int tt = 0; tt < nt; tt += 2) {
        // ---- sub-iter A: compute buf0, stage tile tt+1 -> buf1 ----
        GSTAGE(tt + 1, 16384);
        asm volatile("s_waitcnt vmcnt(8)" ::: "memory");   // tile tt landed
        __builtin_amdgcn_s_barrier();
        __builtin_amdgcn_sched_barrier(0);
        GCOMPUTE(As, Ws);
        __builtin_amdgcn_s_barrier();
        // ---- sub-iter B: compute buf1, stage tile tt+2 -> buf0 ----
        if (tt + 2 < nt) {
            GSTAGE(tt + 2, 0);
            asm volatile("s_waitcnt vmcnt(8)" ::: "memory");
        } else {
            asm volatile("s_waitcnt vmcnt(0)" ::: "memory");
        }
        __builtin_amdgcn_s_barrier();
        __builtin_amdgcn_sched_barrier(0);
        GCOMPUTE(As + 8192, Ws + 8192);
        __builtin_amdgcn_s_barrier();
    }
#undef GSTAGE
#undef GCOMPUTE

#pragma unroll
    for (int i = 0; i < 4; i++) {
        const int gr = m0 + wr + i * 16 + quad * 4;
#pragma unroll
        for (int j = 0; j < 4; j++) {
            const int gc = n0 + wc + j * 16 + l15;
            const float bv = bias[gc];
#pragma unroll
            for (int r = 0; r < 4; r++) {
                float v = acc[i][j][r] + bv;
                if (GELU) v = gelu_fast(v);
                if (RES)  v += res[(size_t)(gr + r) * N + gc];
                if (WF32) outF[(size_t)(gr + r) * N + gc] = v;
                if (WB16) outB[(size_t)(gr + r) * N + gc] = f2b(v);
            }
        }
    }
}

// ---------------------------------------------------------------------------
// Patch-embed MFMA GEMM: A gathered from bf16 image xb, W = conv_w bf16.
// Same dbuf pipeline; A source address is a per-lane gather. nt = 12 (even).
// ---------------------------------------------------------------------------
__global__ __launch_bounds__(256) void patch_mfma_kernel(
    const unsigned short* __restrict__ xb, const unsigned short* __restrict__ W,
    const float* __restrict__ bias, float* __restrict__ outF)
{
    __shared__ unsigned short As[2 * 128 * 64];
    __shared__ unsigned short Ws[2 * 128 * 64];

    const int t    = threadIdx.x;
    const int m0   = blockIdx.x * 128;
    const int n0   = blockIdx.y * 128;
    const int wv   = t >> 6, lane = t & 63;
    const int wr   = (wv >> 1) * 64, wc = (wv & 1) * 64;
    const int l15  = lane & 15, quad = lane >> 4;

    f32x4 acc[4][4];
#pragma unroll
    for (int i = 0; i < 4; i++)
#pragma unroll
        for (int j = 0; j < 4; j++)
#pragma unroll
            for (int r = 0; r < 4; r++) acc[i][j][r] = 0.0f;

    const int srow = wv * 8 + (lane >> 3);
    const int skk  = (((lane & 7) ^ ((lane >> 3) & 7)) * 8);  // swizzled k-chunk
    size_t xoff[4];
#pragma unroll
    for (int s = 0; s < 4; s++) {
        const int m  = m0 + s * 32 + srow;
        const int b  = m >> 10;
        const int idx = m & 1023;
        const int hh = idx >> 5, ww = idx & 31;
        xoff[s] = ((size_t)(b * 3) * 512 + (size_t)(hh * 16)) * 512 + ww * 16;
    }
    const unsigned short* gW = W + (size_t)(n0 + srow) * 768 + skk;
    char* lA = (char*)As + wv * 1024;
    char* lW = (char*)Ws + wv * 1024;

    const int cswz = (l15 & 7) * 8;

#define PSTAGE(tt, BUFOFF)                                                     \
    {                                                                          \
        const int kk = ((tt) << 6) + skk;   /* 8-aligned, within one px row */ \
        const int c  = kk >> 8;                                                \
        const int ph = (kk >> 4) & 15;                                         \
        const int pw = kk & 15;                                                \
        const size_t koff = (size_t)c * 262144 + (size_t)ph * 512 + pw;        \
        _Pragma("unroll")                                                      \
        for (int s = 0; s < 4; s++) {                                          \
            load_lds16(xb + xoff[s] + koff, lA + (BUFOFF) + s * 4096);         \
            load_lds16(gW + (size_t)(s * 32) * 768 + ((tt) << 6),              \
                       lW + (BUFOFF) + s * 4096);                              \
        }                                                                      \
    }

#define PCOMPUTE(Ab, Wb)                                                       \
    {                                                                          \
        _Pragma("unroll")                                                      \
        for (int kh = 0; kh < 2; kh++) {                                       \
            const int coff = (kh * 32 + quad * 8) ^ cswz;                      \
            short8 af[4], wf[4];                                               \
            _Pragma("unroll")                                                  \
            for (int i = 0; i < 4; i++)                                        \
                af[i] = *(const short8*)&(Ab)[(wr + i * 16 + l15) * 64 + coff];\
            _Pragma("unroll")                                                  \
            for (int j = 0; j < 4; j++)                                        \
                wf[j] = *(const short8*)&(Wb)[(wc + j * 16 + l15) * 64 + coff];\
            _Pragma("unroll")                                                  \
            for (int i = 0; i < 4; i++)                                        \
                _Pragma("unroll")                                              \
                for (int j = 0; j < 4; j++)                                    \
                    acc[i][j] = __builtin_amdgcn_mfma_f32_16x16x32_bf16(       \
                        af[i], wf[j], acc[i][j], 0, 0, 0);                     \
        }                                                                      \
    }

    PSTAGE(0, 0);
    for (int tt = 0; tt < 12; tt += 2) {
        PSTAGE(tt + 1, 16384);
        asm volatile("s_waitcnt vmcnt(8)" ::: "memory");
        __builtin_amdgcn_s_barrier();
        __builtin_amdgcn_sched_barrier(0);
        PCOMPUTE(As, Ws);
        __builtin_amdgcn_s_barrier();
        if (tt + 2 < 12) {
            PSTAGE(tt + 2, 0);
            asm volatile("s_waitcnt vmcnt(8)" ::: "memory");
        } else {
            asm volatile("s_waitcnt vmcnt(0)" ::: "memory");
        }
        __builtin_amdgcn_s_barrier();
        __builtin_amdgcn_sched_barrier(0);
        PCOMPUTE(As + 8192, Ws + 8192);
        __builtin_amdgcn_s_barrier();
    }
#undef PSTAGE
#undef PCOMPUTE

#pragma unroll
    for (int i = 0; i < 4; i++) {
        const int gr = m0 + wr + i * 16 + quad * 4;
#pragma unroll
        for (int j = 0; j < 4; j++) {
            const int gc = n0 + wc + j * 16 + l15;
            const float bv = bias[gc];
#pragma unroll
            for (int r = 0; r < 4; r++)
                outF[(size_t)(gr + r) * 256 + gc] = acc[i][j][r] + bv;
        }
    }
}

// ---------------------------------------------------------------------------
// LayerNorm + PE (table lookup). One block = one token (256 features).
// ---------------------------------------------------------------------------
__global__ __launch_bounds__(256) void ln_pe_kernel(
    const float* __restrict__ in, const float* __restrict__ w,
    const float* __restrict__ b, const float* __restrict__ pe_t,
    float* __restrict__ outF, unsigned short* __restrict__ outB)
{
    const int m = blockIdx.x;
    const int d = threadIdx.x;
    float v = in[(size_t)m * 256 + d];

    float s = v, s2 = v * v;
#pragma unroll
    for (int off = 32; off > 0; off >>= 1) {
        s  += __shfl_down(s,  off, 64);
        s2 += __shfl_down(s2, off, 64);
    }
    __shared__ float ss[4], ss2[4], stats[2];
    const int lane = d & 63, wid = d >> 6;
    if (lane == 0) { ss[wid] = s; ss2[wid] = s2; }
    __syncthreads();
    if (d == 0) {
        float a  = ss[0] + ss[1] + ss[2] + ss[3];
        float a2 = ss2[0] + ss2[1] + ss2[2] + ss2[3];
        float mean = a * (1.0f / 256.0f);
        float var  = a2 * (1.0f / 256.0f) - mean * mean;
        stats[0] = mean;
        stats[1] = rsqrtf(var + 1e-5f);
    }
    __syncthreads();
    const float mean = stats[0], rstd = stats[1];

    const int pos = m & 1023;
    float pe = pe_t[pos * 256 + d];

    float o = (v - mean) * rstd * w[d] + b[d] + pe;
    outF[(size_t)m * 256 + d] = o;
    outB[(size_t)m * 256 + d] = f2b(o);
}

// ---------------------------------------------------------------------------
// MFMA windowed attention. One block = one (batch, window, head).
// ---------------------------------------------------------------------------
__global__ __launch_bounds__(256) void attn_mfma_kernel(
    const unsigned short* __restrict__ qkv, unsigned short* __restrict__ out)
{
    __shared__ unsigned short Ps[64 * 72];   // P, stride 72 (b128-aligned, padded)
    __shared__ unsigned short Vt[32 * 72];   // V^T [headdim][key]

    const int blk = blockIdx.x;        // 0..4095
    const int h = blk & 7;
    const int w = (blk >> 3) & 15;
    const int b = blk >> 7;
    const int m_base = b * 1024 + w * 64;

    const int t = threadIdx.x;
    const int wv = t >> 6, lane = t & 63;
    const int l15 = lane & 15, quad = lane >> 4;

    // ---- stage V^T (cooperative, 8 elems/thread) ----
    {
        const int row = t >> 2;             // key 0..63
        const int c0  = (t & 3) * 8;        // headdim chunk
        const unsigned short* src = qkv + (size_t)(m_base + row) * 768 + 512 + h * 32 + c0;
        us8v v = *(const us8v*)src;
#pragma unroll
        for (int j = 0; j < 8; j++) Vt[(c0 + j) * 72 + row] = v[j];
    }

    // ---- QK^T: S strip (16x64) = 4 MFMAs ----
    short8 aq = *(const short8*)(qkv + (size_t)(m_base + wv * 16 + l15) * 768 + h * 32 + quad * 8);
    f32x4 c[4];
#pragma unroll
    for (int j = 0; j < 4; j++) {
        short8 bk = *(const short8*)(qkv + (size_t)(m_base + j * 16 + l15) * 768 + 256 + h * 32 + quad * 8);
        f32x4 z = {0.0f, 0.0f, 0.0f, 0.0f};
        c[j] = __builtin_amdgcn_mfma_f32_16x16x32_bf16(aq, bk, z, 0, 0, 0);
    }

    // ---- softmax over keys (row = quad*4+reg, col = j*16+l15) ----
    const float scale = 0.17677669529663687f; // 1/sqrt(32)
    float sm[4];
#pragma unroll
    for (int r = 0; r < 4; r++) {
        float m0 = -1e30f;
#pragma unroll
        for (int j = 0; j < 4; j++) { c[j][r] *= scale; m0 = fmaxf(m0, c[j][r]); }
#pragma unroll
        for (int d = 1; d < 16; d <<= 1) m0 = fmaxf(m0, __shfl_xor(m0, d, 64));
        float s0 = 0.0f;
#pragma unroll
        for (int j = 0; j < 4; j++) { float e = __expf(c[j][r] - m0); c[j][r] = e; s0 += e; }
#pragma unroll
        for (int d = 1; d < 16; d <<= 1) s0 += __shfl_xor(s0, d, 64);
        sm[r] = __builtin_amdgcn_rcpf(s0);
    }

    // ---- write P (bf16) to LDS ----
#pragma unroll
    for (int r = 0; r < 4; r++) {
        const int prow = wv * 16 + quad * 4 + r;
#pragma unroll
        for (int j = 0; j < 4; j++)
            Ps[prow * 72 + j * 16 + l15] = f2b(c[j][r] * sm[r]);
    }
    __syncthreads();

    // ---- PV: O strip (16x32) = 4 MFMAs ----
    short8 ap0 = *(const short8*)&Ps[(wv * 16 + l15) * 72 + quad * 8];
    short8 ap1 = *(const short8*)&Ps[(wv * 16 + l15) * 72 + 32 + quad * 8];
    f32x4 o[2];
#pragma unroll
    for (int nt = 0; nt < 2; nt++) {
        short8 bv0 = *(const short8*)&Vt[(nt * 16 + l15) * 72 + quad * 8];
        short8 bv1 = *(const short8*)&Vt[(nt * 16 + l15) * 72 + 32 + quad * 8];
        f32x4 z = {0.0f, 0.0f, 0.0f, 0.0f};
        o[nt] = __builtin_amdgcn_mfma_f32_16x16x32_bf16(ap0, bv0, z, 0, 0, 0);
        o[nt] = __builtin_amdgcn_mfma_f32_16x16x32_bf16(ap1, bv1, o[nt], 0, 0, 0);
    }

    // ---- write O (bf16) ----
#pragma unroll
    for (int nt = 0; nt < 2; nt++) {
#pragma unroll
        for (int r = 0; r < 4; r++) {
            const int row = m_base + wv * 16 + quad * 4 + r;
            out[(size_t)row * 256 + h * 32 + nt * 16 + l15] = f2b(o[nt][r]);
        }
    }
}

// ---------------------------------------------------------------------------
// Workspace layout (bytes), total ~186.5 MB (unchanged).
// ---------------------------------------------------------------------------
extern "C" void kernel_launch(void* const* d_in, const int* in_sizes, int n_in,
                              void* d_out, int out_size, void* d_ws, size_t ws_size,
                              hipStream_t stream)
{
    const float* x      = (const float*)d_in[0];
    const float* conv_w = (const float*)d_in[1];
    const float* conv_b = (const float*)d_in[2];
    const float* ln_w   = (const float*)d_in[3];
    const float* ln_b   = (const float*)d_in[4];
    const float* qkv_w  = (const float*)d_in[5];
    const float* qkv_b  = (const float*)d_in[6];
    const float* proj_w = (const float*)d_in[7];
    const float* proj_b = (const float*)d_in[8];
    const float* ff_w1  = (const float*)d_in[9];
    const float* ff_b1  = (const float*)d_in[10];
    const float* ff_w2  = (const float*)d_in[11];
    const float* ff_b2  = (const float*)d_in[12];
    float* out = (float*)d_out;

    char* ws = (char*)d_ws;
    unsigned short* xb    = (unsigned short*)(ws);                 // SLOT_A
    unsigned short* hidb  = (unsigned short*)(ws);                 // SLOT_A reuse
    float*          h0    = (float*)(ws + 67108864);               // SLOT_B
    unsigned short* qkvb  = (unsigned short*)(ws + 67108864);      // SLOT_B reuse
    float*          pe_t  = (float*)(ws + 100663296);              // SLOT_B tail
    float*          h1f   = (float*)(ws + 117440512);
    unsigned short* h1b   = (unsigned short*)(ws + 150994944);     // SLOT_C
    unsigned short* aob   = (unsigned short*)(ws + 150994944);     // SLOT_C reuse
    unsigned short* f1b   = (unsigned short*)(ws + 167772160);     // SLOT_D
    unsigned short* h2b   = (unsigned short*)(ws + 167772160);     // SLOT_D reuse
    unsigned short* wbase = (unsigned short*)(ws + 184549376);
    unsigned short* conv_wb = wbase;                 // 196608
    unsigned short* qkv_wb  = wbase + 196608;        // 196608
    unsigned short* proj_wb = wbase + 393216;        // 65536
    unsigned short* ff_w1b  = wbase + 458752;        // 262144
    unsigned short* ff_w2b  = wbase + 720896;        // 262144

    const int M = M_TOK;
    dim3 blk(256);

    // K0: conversions + PE table
    cvt_f2b_kernel<<<dim3(25165824 / 1024), blk, 0, stream>>>(x, xb, 25165824);
    cvt_weights_kernel<<<dim3(960), blk, 0, stream>>>(
        conv_w, qkv_w, proj_w, ff_w1, ff_w2,
        conv_wb, qkv_wb, proj_wb, ff_w1b, ff_w2b);
    pe_init_kernel<<<dim3(1024), blk, 0, stream>>>(pe_t);

    // K1: patch embed -> h0 (fp32)
    patch_mfma_kernel<<<dim3(M / 128, 2), blk, 0, stream>>>(xb, conv_wb, conv_b, h0);
    // K2: LN + PE -> h1f (fp32 residual) + h1b (bf16)
    ln_pe_kernel<<<dim3(M), blk, 0, stream>>>(h0, ln_w, ln_b, pe_t, h1f, h1b);
    // K3: FFN1a: gelu(h1 @ w1^T + b1) -> hidb (bf16)
    mfma_gemm_kernel<true, false, false, true><<<dim3(M / 128, 8), blk, 0, stream>>>(
        h1b, ff_w1b, ff_b1, nullptr, nullptr, hidb, M, 1024, 256);
    // K4: FFN1b: hidb @ w2^T + b2 -> f1b (bf16)
    mfma_gemm_kernel<false, false, false, true><<<dim3(M / 128, 2), blk, 0, stream>>>(
        hidb, ff_w2b, ff_b2, nullptr, nullptr, f1b, M, 256, 1024);
    // K5: qkv: f1b @ qkv_w^T + qkv_b -> qkvb (bf16)
    mfma_gemm_kernel<false, false, false, true><<<dim3(M / 128, 6), blk, 0, stream>>>(
        f1b, qkv_wb, qkv_b, nullptr, nullptr, qkvb, M, 768, 256);
    // K6: windowed attention (MFMA): qkvb -> aob (bf16)
    attn_mfma_kernel<<<dim3(4096), blk, 0, stream>>>(qkvb, aob);
    // K7: proj + residual(h1f): aob @ proj_w^T + proj_b + h1f -> out + h2b
    mfma_gemm_kernel<false, true, true, true><<<dim3(M / 128, 2), blk, 0, stream>>>(
        aob, proj_wb, proj_b, h1f, out, h2b, M, 256, 256);
    // K8: FFN2a: gelu(h2b @ w1^T + b1) -> hidb (bf16)
    mfma_gemm_kernel<true, false, false, true><<<dim3(M / 128, 8), blk, 0, stream>>>(
        h2b, ff_w1b, ff_b1, nullptr, nullptr, hidb, M, 1024, 256);
    // K9: FFN2b + final residual: hidb @ w2^T + b2 + out -> out
    mfma_gemm_kernel<false, true, true, false><<<dim3(M / 128, 2), blk, 0, stream>>>(
        hidb, ff_w2b, ff_b2, out, out, nullptr, M, 256, 1024);
}